// Round 4
// baseline (4911.021 us; speedup 1.0000x reference)
//
#include <hip/hip_runtime.h>
#include <hip/hip_fp16.h>

#define HDIM 64
#define HFC 32
#define NCLS 10
#define DTILE 16

__device__ inline __half2 u2h2(unsigned int u) {
    __half2 r;
    *reinterpret_cast<unsigned int*>(&r) = u;
    return r;
}

// packed fp16 atomic add (native global_atomic_pk_add_f16 on gfx950)
__device__ inline void h2_atomic_add(__half2* addr, __half2 val) {
    unsafeAtomicAdd(addr, val);
}

// ---------------- degree / normalization ----------------

__global__ void k_deg(const int* __restrict__ dst, float* __restrict__ deg, int E) {
    int e = blockIdx.x * blockDim.x + threadIdx.x;
    if (e < E) atomicAdd(&deg[dst[e]], 1.0f);
}

__global__ void k_dinv(float* __restrict__ deg, int n) {
    int i = blockIdx.x * blockDim.x + threadIdx.x;
    if (i < n) deg[i] = rsqrtf(deg[i] + 1.0f);   // +1 for self-loop
}

// ---------------- layer 1 (2 input features): aggregate x (fp32), then @W1 -> fp16 ----------------

__global__ void k_self2(const float* __restrict__ x, const float* __restrict__ dinv,
                        float* __restrict__ agg, int n) {
    int gid = blockIdx.x * blockDim.x + threadIdx.x;   // over n*2
    if (gid < n * 2) {
        int i = gid >> 1;
        float dv = dinv[i];
        agg[gid] = x[gid] * dv * dv;
    }
}

__global__ void k_edge2(const int* __restrict__ src, const int* __restrict__ dst,
                        const float* __restrict__ x, const float* __restrict__ dinv,
                        float* __restrict__ agg, int E) {
    int e = blockIdx.x * blockDim.x + threadIdx.x;
    if (e >= E) return;
    int s = src[e], d = dst[e];
    float nrm = dinv[s] * dinv[d];
    atomicAdd(&agg[d * 2 + 0], x[s * 2 + 0] * nrm);
    atomicAdd(&agg[d * 2 + 1], x[s * 2 + 1] * nrm);
}

__global__ void k_dense2(const float* __restrict__ agg, const float* __restrict__ W,
                         const float* __restrict__ b, __half* __restrict__ out, long long n) {
    long long gid = (long long)blockIdx.x * blockDim.x + threadIdx.x;  // n*64
    if (gid >= n * HDIM) return;
    int f = (int)(gid & 63);
    long long i = gid >> 6;
    float a0 = agg[i * 2 + 0], a1 = agg[i * 2 + 1];
    float acc = fmaf(a0, W[f], fmaf(a1, W[HDIM + f], b[f]));
    out[gid] = __float2half(fmaxf(acc, 0.0f));
}

// ---------------- layers 2/3: fp16 feature buffers ----------------

// writes EVERY element of agg (self-loop term) => serves as the init, no memset needed
__global__ void k_self64h(const __half* __restrict__ h, const float* __restrict__ dinv,
                          __half* __restrict__ agg, long long n) {
    long long gid = (long long)blockIdx.x * blockDim.x + threadIdx.x;  // n*8 (8 halfs each)
    if (gid >= n * 8) return;
    float dv = dinv[gid >> 3];
    dv *= dv;
    const uint4 v = *reinterpret_cast<const uint4*>(h + gid * 8);
    __half2 o[4];
    {
        float2 f;
        f = __half22float2(u2h2(v.x)); o[0] = __floats2half2_rn(f.x * dv, f.y * dv);
        f = __half22float2(u2h2(v.y)); o[1] = __floats2half2_rn(f.x * dv, f.y * dv);
        f = __half22float2(u2h2(v.z)); o[2] = __floats2half2_rn(f.x * dv, f.y * dv);
        f = __half22float2(u2h2(v.w)); o[3] = __floats2half2_rn(f.x * dv, f.y * dv);
    }
    *reinterpret_cast<uint4*>(agg + gid * 8) = *reinterpret_cast<const uint4*>(o);
}

__global__ void k_edge64h(const int* __restrict__ src, const int* __restrict__ dst,
                          const float* __restrict__ dinv, const __half* __restrict__ h,
                          __half* __restrict__ agg, int E) {
    long long gid = (long long)blockIdx.x * blockDim.x + threadIdx.x;  // E*16
    if (gid >= (long long)E * 16) return;
    int e = (int)(gid >> 4);
    int c = (int)(gid & 15);
    int s = src[e], d = dst[e];
    float nrm = dinv[s] * dinv[d];
    const uint2 v = *reinterpret_cast<const uint2*>(h + ((long long)s << 6) + (c << 2));
    float2 f0 = __half22float2(u2h2(v.x));
    float2 f1 = __half22float2(u2h2(v.y));
    __half2* a = reinterpret_cast<__half2*>(agg + ((long long)d << 6) + (c << 2));
    h2_atomic_add(a + 0, __floats2half2_rn(f0.x * nrm, f0.y * nrm));
    h2_atomic_add(a + 1, __floats2half2_rn(f1.x * nrm, f1.y * nrm));
}

__global__ void k_dense64h(const __half* __restrict__ in, const float* __restrict__ W,
                           const float* __restrict__ b, __half* __restrict__ out, long long n) {
    __shared__ float sW[HDIM * HDIM];
    __shared__ float sIn[DTILE * HDIM];
    __shared__ float sB[HDIM];
    for (int i = threadIdx.x; i < HDIM * HDIM; i += blockDim.x) sW[i] = W[i];
    if (threadIdx.x < HDIM) sB[threadIdx.x] = b[threadIdx.x];
    long long ntiles = (n + DTILE - 1) / DTILE;
    int f  = threadIdx.x & 63;
    int ng = threadIdx.x >> 6;
    for (long long tile = blockIdx.x; tile < ntiles; tile += gridDim.x) {
        __syncthreads();   // covers sW load on first iter, sIn reuse after
        long long base = tile * (DTILE * HDIM);
        long long rem  = n * HDIM - base;
        int lim = (int)((rem < DTILE * HDIM) ? rem : (DTILE * HDIM));
        for (int i = threadIdx.x; i < DTILE * HDIM; i += blockDim.x)
            sIn[i] = (i < lim) ? __half2float(in[base + i]) : 0.0f;
        __syncthreads();
        for (int ii = ng; ii < DTILE; ii += 4) {
            float acc = sB[f];
            #pragma unroll
            for (int k = 0; k < HDIM; ++k)
                acc = fmaf(sIn[ii * HDIM + k], sW[k * HDIM + f], acc);
            long long node = tile * DTILE + ii;
            if (node < n) out[node * HDIM + f] = __float2half(fmaxf(acc, 0.0f));
        }
    }
}

// ---------------- pooling / batchnorm / head ----------------

__global__ void k_poolh(const __half* __restrict__ h, const int* __restrict__ batch,
                        float* __restrict__ pooled, float* __restrict__ cnt, long long n) {
    long long gid = (long long)blockIdx.x * blockDim.x + threadIdx.x;  // n*16
    if (gid >= n * 16) return;
    long long node = gid >> 4;
    int c = (int)(gid & 15);
    int g = batch[node];
    const uint2 v = *reinterpret_cast<const uint2*>(h + (node << 6) + (c << 2));
    float2 f0 = __half22float2(u2h2(v.x));
    float2 f1 = __half22float2(u2h2(v.y));
    float* p = pooled + (long long)g * HDIM + (c << 2);
    atomicAdd(p + 0, f0.x);
    atomicAdd(p + 1, f0.y);
    atomicAdd(p + 2, f1.x);
    atomicAdd(p + 3, f1.y);
    if (c == 0) atomicAdd(&cnt[g], 1.0f);
}

__global__ void k_bnstats(const float* __restrict__ pooled, const float* __restrict__ cnt,
                          const float* __restrict__ gamma, const float* __restrict__ beta,
                          float* __restrict__ scale, float* __restrict__ shift, int G) {
    int f = blockIdx.x;   // 64 blocks, one per feature
    __shared__ float ss[256], ss2[256];
    float s = 0.0f, s2 = 0.0f;
    for (int g = threadIdx.x; g < G; g += blockDim.x) {
        float c = cnt[g];
        float v = pooled[(long long)g * HDIM + f] / fmaxf(c, 1.0f);
        s += v; s2 += v * v;
    }
    ss[threadIdx.x] = s; ss2[threadIdx.x] = s2;
    __syncthreads();
    for (int off = 128; off > 0; off >>= 1) {
        if (threadIdx.x < off) {
            ss[threadIdx.x]  += ss[threadIdx.x + off];
            ss2[threadIdx.x] += ss2[threadIdx.x + off];
        }
        __syncthreads();
    }
    if (threadIdx.x == 0) {
        float mean = ss[0] / (float)G;
        float var  = ss2[0] / (float)G - mean * mean;
        float rstd = rsqrtf(var + 1e-5f);
        float sc = gamma[f] * rstd;
        scale[f] = sc;
        shift[f] = beta[f] - mean * sc;
    }
}

__global__ void k_head(const float* __restrict__ pooled, const float* __restrict__ cnt,
                       const float* __restrict__ scale, const float* __restrict__ shift,
                       const float* __restrict__ fcW1, const float* __restrict__ fcb1,
                       const float* __restrict__ fcW2, const float* __restrict__ fcb2,
                       float* __restrict__ out, int G) {
    __shared__ float sW1[HDIM * HFC];
    __shared__ float sW2[HFC * NCLS];
    __shared__ float sb1[HFC], sb2[NCLS], ssc[HDIM], ssh[HDIM];
    for (int i = threadIdx.x; i < HDIM * HFC; i += blockDim.x) sW1[i] = fcW1[i];
    for (int i = threadIdx.x; i < HFC * NCLS; i += blockDim.x) sW2[i] = fcW2[i];
    if (threadIdx.x < HFC)  sb1[threadIdx.x] = fcb1[threadIdx.x];
    if (threadIdx.x < NCLS) sb2[threadIdx.x] = fcb2[threadIdx.x];
    if (threadIdx.x < HDIM) { ssc[threadIdx.x] = scale[threadIdx.x]; ssh[threadIdx.x] = shift[threadIdx.x]; }
    __syncthreads();
    int g = blockIdx.x * blockDim.x + threadIdx.x;
    if (g >= G) return;
    float inv = 1.0f / fmaxf(cnt[g], 1.0f);
    float bn[HDIM];
    #pragma unroll
    for (int f = 0; f < HDIM; ++f)
        bn[f] = pooled[(long long)g * HDIM + f] * inv * ssc[f] + ssh[f];
    float hfc[HFC];
    #pragma unroll
    for (int j = 0; j < HFC; ++j) {
        float a = sb1[j];
        #pragma unroll
        for (int f = 0; f < HDIM; ++f) a = fmaf(bn[f], sW1[f * HFC + j], a);
        hfc[j] = fmaxf(a, 0.0f);
    }
    float lg[NCLS];
    float mx = -1e30f;
    #pragma unroll
    for (int c = 0; c < NCLS; ++c) {
        float a = sb2[c];
        #pragma unroll
        for (int j = 0; j < HFC; ++j) a = fmaf(hfc[j], sW2[j * NCLS + c], a);
        lg[c] = a;
        mx = fmaxf(mx, a);
    }
    float se = 0.0f;
    #pragma unroll
    for (int c = 0; c < NCLS; ++c) se += expf(lg[c] - mx);
    float lse = mx + logf(se);
    #pragma unroll
    for (int c = 0; c < NCLS; ++c) out[(long long)g * NCLS + c] = lg[c] - lse;
}

// ---------------- launch ----------------

extern "C" void kernel_launch(void* const* d_in, const int* in_sizes, int n_in,
                              void* d_out, int out_size, void* d_ws, size_t ws_size,
                              hipStream_t stream) {
    const float* x     = (const float*)d_in[0];
    const int*   ei    = (const int*)d_in[1];
    const int*   batch = (const int*)d_in[2];
    const float* W1    = (const float*)d_in[3];
    const float* b1    = (const float*)d_in[4];
    const float* W2    = (const float*)d_in[5];
    const float* b2    = (const float*)d_in[6];
    const float* W3    = (const float*)d_in[7];
    const float* b3    = (const float*)d_in[8];
    const float* gamma = (const float*)d_in[9];
    const float* beta  = (const float*)d_in[10];
    const float* fcW1  = (const float*)d_in[11];
    const float* fcb1  = (const float*)d_in[12];
    const float* fcW2  = (const float*)d_in[13];
    const float* fcb2  = (const float*)d_in[14];

    const long long n = in_sizes[2];        // N nodes
    const int E = in_sizes[1] / 2;          // directed edges
    const int G = out_size / NCLS;          // graphs
    const int* src = ei;
    const int* dst = ei + E;

    // workspace layout (~204 MB):
    //   dinv   : n fp32
    //   agg2   : 2n fp32
    //   pooled : G*64 fp32 ; cnt : G fp32 ; scale/shift : 64+64 fp32
    //   hA, hB : 64n fp16 each
    float* dinv   = (float*)d_ws;
    float* agg2   = dinv + n;
    float* pooled = agg2 + 2 * n;
    float* cnt    = pooled + (long long)G * HDIM;
    float* scale  = cnt + G;
    float* shift  = scale + HDIM;
    // 256B-align the fp16 region
    uintptr_t hbase = (uintptr_t)(shift + HDIM);
    hbase = (hbase + 255) & ~(uintptr_t)255;
    __half* hA = (__half*)hbase;
    __half* hB = hA + (long long)HDIM * n;

    (void)hipMemsetAsync(dinv, 0, n * sizeof(float), stream);
    (void)hipMemsetAsync(pooled, 0, ((long long)G * HDIM + G) * sizeof(float), stream);

    const int B = 256;
    k_deg<<<(E + B - 1) / B, B, 0, stream>>>(dst, dinv, E);
    k_dinv<<<(int)((n + B - 1) / B), B, 0, stream>>>(dinv, (int)n);

    // layer 1 (2 input features, fp32 agg)
    k_self2<<<(int)((2 * n + B - 1) / B), B, 0, stream>>>(x, dinv, agg2, (int)n);
    k_edge2<<<(E + B - 1) / B, B, 0, stream>>>(src, dst, x, dinv, agg2, E);
    k_dense2<<<(int)((HDIM * n + B - 1) / B), B, 0, stream>>>(agg2, W1, b1, hA, n);

    // layer 2: scatter hA -> hB, dense hB -> hA
    k_self64h<<<(int)((n * 8 + B - 1) / B), B, 0, stream>>>(hA, dinv, hB, n);
    k_edge64h<<<(int)(((long long)E * 16 + B - 1) / B), B, 0, stream>>>(src, dst, dinv, hA, hB, E);
    k_dense64h<<<4096, B, 0, stream>>>(hB, W2, b2, hA, n);

    // layer 3
    k_self64h<<<(int)((n * 8 + B - 1) / B), B, 0, stream>>>(hA, dinv, hB, n);
    k_edge64h<<<(int)(((long long)E * 16 + B - 1) / B), B, 0, stream>>>(src, dst, dinv, hA, hB, E);
    k_dense64h<<<4096, B, 0, stream>>>(hB, W3, b3, hA, n);

    // pooling + BN + head
    k_poolh<<<(int)((n * 16 + B - 1) / B), B, 0, stream>>>(hA, batch, pooled, cnt, n);
    k_bnstats<<<HDIM, B, 0, stream>>>(pooled, cnt, gamma, beta, scale, shift, G);
    k_head<<<(G + B - 1) / B, B, 0, stream>>>(pooled, cnt, scale, shift,
                                              fcW1, fcb1, fcW2, fcb2, (float*)d_out, G);
}

// Round 5
// 2601.030 us; speedup vs baseline: 1.8881x; 1.8881x over previous
//
#include <hip/hip_runtime.h>
#include <hip/hip_fp16.h>

#define HDIM 64
#define HFC 32
#define NCLS 10
#define DTILE 16

__device__ inline __half2 u2h2(unsigned int u) {
    __half2 r;
    *reinterpret_cast<unsigned int*>(&r) = u;
    return r;
}
__device__ inline unsigned int h22u(__half2 h) {
    return *reinterpret_cast<unsigned int*>(&h);
}
__device__ inline void h2_atomic_add(__half2* addr, __half2 val) {
    unsafeAtomicAdd(addr, val);
}

// ================= CSR build =================

__global__ void k_count(const int* __restrict__ dst, int* __restrict__ degi, int E) {
    int e = blockIdx.x * blockDim.x + threadIdx.x;
    if (e < E) atomicAdd(&degi[dst[e]], 1);
}

__global__ void k_dinv2(const int* __restrict__ degi, float* __restrict__ dinv, int n) {
    int i = blockIdx.x * blockDim.x + threadIdx.x;
    if (i < n) dinv[i] = rsqrtf((float)degi[i] + 1.0f);   // +1 self-loop
}

// block partial sums over 1024-element chunks
__global__ void k_scan1(const int* __restrict__ degi, int* __restrict__ bsum, int n) {
    __shared__ int red[256];
    int base = blockIdx.x * 1024;
    int s = 0;
    for (int i = threadIdx.x; i < 1024; i += 256) {
        int idx = base + i;
        s += (idx < n) ? degi[idx] : 0;
    }
    red[threadIdx.x] = s; __syncthreads();
    for (int o = 128; o > 0; o >>= 1) {
        if (threadIdx.x < o) red[threadIdx.x] += red[threadIdx.x + o];
        __syncthreads();
    }
    if (threadIdx.x == 0) bsum[blockIdx.x] = red[0];
}

// single-block exclusive scan of block sums (nb <= 1024)
__global__ void k_scan2(int* __restrict__ bsum, int nb) {
    __shared__ int sh[1024];
    int v = (threadIdx.x < nb) ? bsum[threadIdx.x] : 0;
    sh[threadIdx.x] = v; __syncthreads();
    for (int o = 1; o < 1024; o <<= 1) {
        int t = (threadIdx.x >= (unsigned)o) ? sh[threadIdx.x - o] : 0;
        __syncthreads();
        sh[threadIdx.x] += t;
        __syncthreads();
    }
    if (threadIdx.x < nb) bsum[threadIdx.x] = sh[threadIdx.x] - v;  // exclusive
}

// full scan: rowptr[i+1] = inclusive_scan(degi)[i]; rowptr[0]=0
__global__ void k_scan3(const int* __restrict__ degi, const int* __restrict__ bsum,
                        int* __restrict__ rowptr, int n) {
    __shared__ int red[256];
    int bbase = bsum[blockIdx.x];
    int idx0 = blockIdx.x * 1024 + threadIdx.x * 4;
    int d0 = (idx0 + 0 < n) ? degi[idx0 + 0] : 0;
    int d1 = (idx0 + 1 < n) ? degi[idx0 + 1] : 0;
    int d2 = (idx0 + 2 < n) ? degi[idx0 + 2] : 0;
    int d3 = (idx0 + 3 < n) ? degi[idx0 + 3] : 0;
    int tsum = d0 + d1 + d2 + d3;
    red[threadIdx.x] = tsum; __syncthreads();
    for (int o = 1; o < 256; o <<= 1) {
        int t = (threadIdx.x >= (unsigned)o) ? red[threadIdx.x - o] : 0;
        __syncthreads();
        red[threadIdx.x] += t;
        __syncthreads();
    }
    int texcl = red[threadIdx.x] - tsum + bbase;
    if (idx0 + 0 < n) rowptr[idx0 + 1] = texcl + d0;
    if (idx0 + 1 < n) rowptr[idx0 + 2] = texcl + d0 + d1;
    if (idx0 + 2 < n) rowptr[idx0 + 3] = texcl + d0 + d1 + d2;
    if (idx0 + 3 < n) rowptr[idx0 + 4] = texcl + tsum;
    if (blockIdx.x == 0 && threadIdx.x == 0) rowptr[0] = 0;
}

__global__ void k_copycur(const int* __restrict__ rowptr, int* __restrict__ cursor, int n) {
    int i = blockIdx.x * blockDim.x + threadIdx.x;
    if (i < n) cursor[i] = rowptr[i];
}

__global__ void k_fill(const int* __restrict__ src, const int* __restrict__ dst,
                       int* __restrict__ cursor, int* __restrict__ col, int E) {
    int e = blockIdx.x * blockDim.x + threadIdx.x;
    if (e >= E) return;
    int p = atomicAdd(&cursor[dst[e]], 1);
    col[p] = src[e];
}

// ================= layer 1 (2 fp32 features) =================

__global__ void k_xs(const float* __restrict__ x, const float* __restrict__ dinv,
                     float* __restrict__ xs, int n2) {
    int gid = blockIdx.x * blockDim.x + threadIdx.x;
    if (gid < n2) xs[gid] = x[gid] * dinv[gid >> 1];
}

__global__ void k_gather1(const int* __restrict__ rowptr, const int* __restrict__ col,
                          const float* __restrict__ xs, const float* __restrict__ dinv,
                          float* __restrict__ agg2, int n) {
    int d = blockIdx.x * blockDim.x + threadIdx.x;
    if (d >= n) return;
    const float2* xs2 = reinterpret_cast<const float2*>(xs);
    float2 v = xs2[d];
    float a0 = v.x, a1 = v.y;
    int e0 = rowptr[d], e1 = rowptr[d + 1];
    for (int e = e0; e < e1; ++e) {
        float2 w = xs2[col[e]];
        a0 += w.x; a1 += w.y;
    }
    float dv = dinv[d];
    agg2[2 * d] = a0 * dv;
    agg2[2 * d + 1] = a1 * dv;
}

// dense 2->64, optional dinv scaling of output
__global__ void k_dense2(const float* __restrict__ agg, const float* __restrict__ W,
                         const float* __restrict__ b, const float* __restrict__ dinv,
                         __half* __restrict__ out, long long n) {
    long long gid = (long long)blockIdx.x * blockDim.x + threadIdx.x;  // n*64
    if (gid >= n * HDIM) return;
    int f = (int)(gid & 63);
    long long i = gid >> 6;
    float a0 = agg[i * 2 + 0], a1 = agg[i * 2 + 1];
    float acc = fmaf(a0, W[f], fmaf(a1, W[HDIM + f], b[f]));
    float sc = dinv ? dinv[i] : 1.0f;
    out[gid] = __float2half(fmaxf(acc, 0.0f) * sc);
}

// ================= layers 2/3 gather (no atomics) =================

__global__ void k_gather64(const int* __restrict__ rowptr, const int* __restrict__ col,
                           const __half* __restrict__ hs, const float* __restrict__ dinv,
                           __half* __restrict__ agg, long long n) {
    long long gid = (long long)blockIdx.x * blockDim.x + threadIdx.x;  // n*16
    if (gid >= n * 16) return;
    int d = (int)(gid >> 4);
    int q = (int)(gid & 15);
    const uint2* rows = reinterpret_cast<const uint2*>(hs);
    uint2 v = rows[(long long)d * 16 + q];
    float2 f0 = __half22float2(u2h2(v.x));
    float2 f1 = __half22float2(u2h2(v.y));
    float a0 = f0.x, a1 = f0.y, a2 = f1.x, a3 = f1.y;
    int e0 = rowptr[d], e1 = rowptr[d + 1];
    for (int e = e0; e < e1; ++e) {
        int s = col[e];
        uint2 w = rows[(long long)s * 16 + q];
        float2 g0 = __half22float2(u2h2(w.x));
        float2 g1 = __half22float2(u2h2(w.y));
        a0 += g0.x; a1 += g0.y; a2 += g1.x; a3 += g1.y;
    }
    float dv = dinv[d];
    uint2 o;
    o.x = h22u(__floats2half2_rn(a0 * dv, a1 * dv));
    o.y = h22u(__floats2half2_rn(a2 * dv, a3 * dv));
    reinterpret_cast<uint2*>(agg)[(long long)d * 16 + q] = o;
}

// dense 64->64, optional dinv scaling; supports in == out (tile-local)
__global__ void k_dense64s(const __half* in, const float* __restrict__ W,
                           const float* __restrict__ b, const float* __restrict__ dinv,
                           __half* out, long long n) {
    __shared__ float sW[HDIM * HDIM];
    __shared__ float sIn[DTILE * HDIM];
    __shared__ float sB[HDIM];
    for (int i = threadIdx.x; i < HDIM * HDIM; i += blockDim.x) sW[i] = W[i];
    if (threadIdx.x < HDIM) sB[threadIdx.x] = b[threadIdx.x];
    long long ntiles = (n + DTILE - 1) / DTILE;
    int f  = threadIdx.x & 63;
    int ng = threadIdx.x >> 6;
    for (long long tile = blockIdx.x; tile < ntiles; tile += gridDim.x) {
        __syncthreads();
        long long base = tile * (DTILE * HDIM);
        long long rem  = n * HDIM - base;
        int lim = (int)((rem < DTILE * HDIM) ? rem : (DTILE * HDIM));
        for (int i = threadIdx.x; i < DTILE * HDIM; i += blockDim.x)
            sIn[i] = (i < lim) ? __half2float(in[base + i]) : 0.0f;
        __syncthreads();
        for (int ii = ng; ii < DTILE; ii += 4) {
            float acc = sB[f];
            #pragma unroll
            for (int k = 0; k < HDIM; ++k)
                acc = fmaf(sIn[ii * HDIM + k], sW[k * HDIM + f], acc);
            long long node = tile * DTILE + ii;
            if (node < n) {
                float sc = dinv ? dinv[node] : 1.0f;
                out[node * HDIM + f] = __float2half(fmaxf(acc, 0.0f) * sc);
            }
        }
    }
}

// ================= fallback (atomic) aggregation kernels =================

__global__ void k_self2(const float* __restrict__ x, const float* __restrict__ dinv,
                        float* __restrict__ agg, int n) {
    int gid = blockIdx.x * blockDim.x + threadIdx.x;
    if (gid < n * 2) {
        int i = gid >> 1;
        float dv = dinv[i];
        agg[gid] = x[gid] * dv * dv;
    }
}

__global__ void k_edge2(const int* __restrict__ src, const int* __restrict__ dst,
                        const float* __restrict__ x, const float* __restrict__ dinv,
                        float* __restrict__ agg, int E) {
    int e = blockIdx.x * blockDim.x + threadIdx.x;
    if (e >= E) return;
    int s = src[e], d = dst[e];
    float nrm = dinv[s] * dinv[d];
    atomicAdd(&agg[d * 2 + 0], x[s * 2 + 0] * nrm);
    atomicAdd(&agg[d * 2 + 1], x[s * 2 + 1] * nrm);
}

__global__ void k_self64h(const __half* __restrict__ h, const float* __restrict__ dinv,
                          __half* __restrict__ agg, long long n) {
    long long gid = (long long)blockIdx.x * blockDim.x + threadIdx.x;  // n*8
    if (gid >= n * 8) return;
    float dv = dinv[gid >> 3];
    dv *= dv;
    const uint4 v = *reinterpret_cast<const uint4*>(h + gid * 8);
    __half2 o[4];
    {
        float2 f;
        f = __half22float2(u2h2(v.x)); o[0] = __floats2half2_rn(f.x * dv, f.y * dv);
        f = __half22float2(u2h2(v.y)); o[1] = __floats2half2_rn(f.x * dv, f.y * dv);
        f = __half22float2(u2h2(v.z)); o[2] = __floats2half2_rn(f.x * dv, f.y * dv);
        f = __half22float2(u2h2(v.w)); o[3] = __floats2half2_rn(f.x * dv, f.y * dv);
    }
    *reinterpret_cast<uint4*>(agg + gid * 8) = *reinterpret_cast<const uint4*>(o);
}

__global__ void k_edge64h(const int* __restrict__ src, const int* __restrict__ dst,
                          const float* __restrict__ dinv, const __half* __restrict__ h,
                          __half* __restrict__ agg, int E) {
    long long gid = (long long)blockIdx.x * blockDim.x + threadIdx.x;  // E*16
    if (gid >= (long long)E * 16) return;
    int e = (int)(gid >> 4);
    int c = (int)(gid & 15);
    int s = src[e], d = dst[e];
    float nrm = dinv[s] * dinv[d];
    const uint2 v = *reinterpret_cast<const uint2*>(h + ((long long)s << 6) + (c << 2));
    float2 f0 = __half22float2(u2h2(v.x));
    float2 f1 = __half22float2(u2h2(v.y));
    __half2* a = reinterpret_cast<__half2*>(agg + ((long long)d << 6) + (c << 2));
    h2_atomic_add(a + 0, __floats2half2_rn(f0.x * nrm, f0.y * nrm));
    h2_atomic_add(a + 1, __floats2half2_rn(f1.x * nrm, f1.y * nrm));
}

// ================= pooling (segmented, batch sorted) / BN / head =================

__global__ void k_start(const int* __restrict__ batch, int* __restrict__ startArr,
                        int n, int G) {
    int g = blockIdx.x * blockDim.x + threadIdx.x;
    if (g > G) return;
    int lo = 0, hi = n;
    while (lo < hi) {
        int mid = (lo + hi) >> 1;
        if (batch[mid] < g) lo = mid + 1; else hi = mid;
    }
    startArr[g] = lo;   // first index with batch[i] >= g ; g==G -> n
}

__global__ void k_pool_seg(const __half* __restrict__ h, const int* __restrict__ startArr,
                           float* __restrict__ pooled, int G) {
    int g = blockIdx.x;
    int f = threadIdx.x;   // 64 threads
    int s = startArr[g], e = startArr[g + 1];
    float acc = 0.0f;
    for (int i = s; i < e; ++i) acc += __half2float(h[(long long)i * HDIM + f]);
    int c = e - s;
    pooled[(long long)g * HDIM + f] = acc / (float)(c > 0 ? c : 1);
}

__global__ void k_bnstats(const float* __restrict__ pooled,
                          const float* __restrict__ gamma, const float* __restrict__ beta,
                          float* __restrict__ scale, float* __restrict__ shift, int G) {
    int f = blockIdx.x;
    __shared__ float ss[256], ss2[256];
    float s = 0.0f, s2 = 0.0f;
    for (int g = threadIdx.x; g < G; g += blockDim.x) {
        float v = pooled[(long long)g * HDIM + f];
        s += v; s2 += v * v;
    }
    ss[threadIdx.x] = s; ss2[threadIdx.x] = s2;
    __syncthreads();
    for (int off = 128; off > 0; off >>= 1) {
        if (threadIdx.x < off) {
            ss[threadIdx.x]  += ss[threadIdx.x + off];
            ss2[threadIdx.x] += ss2[threadIdx.x + off];
        }
        __syncthreads();
    }
    if (threadIdx.x == 0) {
        float mean = ss[0] / (float)G;
        float var  = ss2[0] / (float)G - mean * mean;
        float rstd = rsqrtf(var + 1e-5f);
        float sc = gamma[f] * rstd;
        scale[f] = sc;
        shift[f] = beta[f] - mean * sc;
    }
}

__global__ void k_head(const float* __restrict__ pooled,
                       const float* __restrict__ scale, const float* __restrict__ shift,
                       const float* __restrict__ fcW1, const float* __restrict__ fcb1,
                       const float* __restrict__ fcW2, const float* __restrict__ fcb2,
                       float* __restrict__ out, int G) {
    __shared__ float sW1[HDIM * HFC];
    __shared__ float sW2[HFC * NCLS];
    __shared__ float sb1[HFC], sb2[NCLS], ssc[HDIM], ssh[HDIM];
    for (int i = threadIdx.x; i < HDIM * HFC; i += blockDim.x) sW1[i] = fcW1[i];
    for (int i = threadIdx.x; i < HFC * NCLS; i += blockDim.x) sW2[i] = fcW2[i];
    if (threadIdx.x < HFC)  sb1[threadIdx.x] = fcb1[threadIdx.x];
    if (threadIdx.x < NCLS) sb2[threadIdx.x] = fcb2[threadIdx.x];
    if (threadIdx.x < HDIM) { ssc[threadIdx.x] = scale[threadIdx.x]; ssh[threadIdx.x] = shift[threadIdx.x]; }
    __syncthreads();
    int g = blockIdx.x * blockDim.x + threadIdx.x;
    if (g >= G) return;
    float bn[HDIM];
    #pragma unroll
    for (int f = 0; f < HDIM; ++f)
        bn[f] = pooled[(long long)g * HDIM + f] * ssc[f] + ssh[f];
    float hfc[HFC];
    #pragma unroll
    for (int j = 0; j < HFC; ++j) {
        float a = sb1[j];
        #pragma unroll
        for (int f = 0; f < HDIM; ++f) a = fmaf(bn[f], sW1[f * HFC + j], a);
        hfc[j] = fmaxf(a, 0.0f);
    }
    float lg[NCLS];
    float mx = -1e30f;
    #pragma unroll
    for (int c = 0; c < NCLS; ++c) {
        float a = sb2[c];
        #pragma unroll
        for (int j = 0; j < HFC; ++j) a = fmaf(hfc[j], sW2[j * NCLS + c], a);
        lg[c] = a;
        mx = fmaxf(mx, a);
    }
    float se = 0.0f;
    #pragma unroll
    for (int c = 0; c < NCLS; ++c) se += expf(lg[c] - mx);
    float lse = mx + logf(se);
    #pragma unroll
    for (int c = 0; c < NCLS; ++c) out[(long long)g * NCLS + c] = lg[c] - lse;
}

// ================= launch =================

static inline char* bump(char*& p, size_t bytes) {
    char* r = p;
    p += (bytes + 255) & ~(size_t)255;
    return r;
}

extern "C" void kernel_launch(void* const* d_in, const int* in_sizes, int n_in,
                              void* d_out, int out_size, void* d_ws, size_t ws_size,
                              hipStream_t stream) {
    const float* x     = (const float*)d_in[0];
    const int*   ei    = (const int*)d_in[1];
    const int*   batch = (const int*)d_in[2];
    const float* W1    = (const float*)d_in[3];
    const float* b1    = (const float*)d_in[4];
    const float* W2    = (const float*)d_in[5];
    const float* b2    = (const float*)d_in[6];
    const float* W3    = (const float*)d_in[7];
    const float* b3    = (const float*)d_in[8];
    const float* gamma = (const float*)d_in[9];
    const float* beta  = (const float*)d_in[10];
    const float* fcW1  = (const float*)d_in[11];
    const float* fcb1  = (const float*)d_in[12];
    const float* fcW2  = (const float*)d_in[13];
    const float* fcb2  = (const float*)d_in[14];

    const long long n = in_sizes[2];
    const int ni = (int)n;
    const int E = in_sizes[1] / 2;
    const int G = out_size / NCLS;
    const int* src = ei;
    const int* dst = ei + E;
    const int B = 256;
    const int nb1024 = (ni + 1023) / 1024;   // scan blocks (<=1024)

    // ---- main (CSR gather) layout ----
    size_t need_main;
    {
        char* p = (char*)0;
        bump(p, n * 4);              // degi / cursor
        bump(p, (n + 1) * 4);        // rowptr
        bump(p, n * 4);              // dinv
        bump(p, 2 * n * 4);          // xs
        bump(p, 2 * n * 4);          // agg2
        bump(p, 1024 * 4);           // bsum
        bump(p, (size_t)(G + 1) * 4);// start
        bump(p, (size_t)G * HDIM * 4); // pooled
        bump(p, 2 * HDIM * 4);       // scale+shift
        bump(p, (size_t)HDIM * n * 2); // hA
        bump(p, (size_t)HDIM * n * 2); // hB
        bump(p, (size_t)E * 4);      // col
        need_main = (size_t)p;
    }

    if (ws_size >= need_main) {
        char* p = (char*)d_ws;
        int*   degi   = (int*)bump(p, n * 4);          // reused as cursor after scan
        int*   rowptr = (int*)bump(p, (n + 1) * 4);
        float* dinv   = (float*)bump(p, n * 4);
        float* xs     = (float*)bump(p, 2 * n * 4);
        float* agg2   = (float*)bump(p, 2 * n * 4);
        int*   bsum   = (int*)bump(p, 1024 * 4);
        int*   startA = (int*)bump(p, (size_t)(G + 1) * 4);
        float* pooled = (float*)bump(p, (size_t)G * HDIM * 4);
        float* scale  = (float*)bump(p, 2 * HDIM * 4);
        float* shift  = scale + HDIM;
        __half* hA    = (__half*)bump(p, (size_t)HDIM * n * 2);
        __half* hB    = (__half*)bump(p, (size_t)HDIM * n * 2);
        int*   col    = (int*)bump(p, (size_t)E * 4);

        (void)hipMemsetAsync(degi, 0, n * 4, stream);

        // CSR build
        k_count<<<(E + B - 1) / B, B, 0, stream>>>(dst, degi, E);
        k_dinv2<<<(ni + B - 1) / B, B, 0, stream>>>(degi, dinv, ni);
        k_scan1<<<nb1024, B, 0, stream>>>(degi, bsum, ni);
        k_scan2<<<1, 1024, 0, stream>>>(bsum, nb1024);
        k_scan3<<<nb1024, B, 0, stream>>>(degi, bsum, rowptr, ni);
        k_copycur<<<(ni + B - 1) / B, B, 0, stream>>>(rowptr, degi, ni);  // degi = cursor
        k_fill<<<(E + B - 1) / B, B, 0, stream>>>(src, dst, degi, col, E);

        // graph boundaries
        k_start<<<(G + 1 + B - 1) / B, B, 0, stream>>>(batch, startA, ni, G);

        // layer 1
        k_xs<<<(2 * ni + B - 1) / B, B, 0, stream>>>(x, dinv, xs, 2 * ni);
        k_gather1<<<(ni + B - 1) / B, B, 0, stream>>>(rowptr, col, xs, dinv, agg2, ni);
        k_dense2<<<(int)((HDIM * n + B - 1) / B), B, 0, stream>>>(agg2, W1, b1, dinv, hA, n);

        // layer 2: gather hA->hB, dense in-place (scaled)
        k_gather64<<<(int)((n * 16 + B - 1) / B), B, 0, stream>>>(rowptr, col, hA, dinv, hB, n);
        k_dense64s<<<4096, B, 0, stream>>>(hB, W2, b2, dinv, hB, n);

        // layer 3: gather hB->hA, dense in-place (unscaled output = h3)
        k_gather64<<<(int)((n * 16 + B - 1) / B), B, 0, stream>>>(rowptr, col, hB, dinv, hA, n);
        k_dense64s<<<4096, B, 0, stream>>>(hA, W3, b3, nullptr, hA, n);

        // pool + BN + head
        k_pool_seg<<<G, HDIM, 0, stream>>>(hA, startA, pooled, G);
        k_bnstats<<<HDIM, B, 0, stream>>>(pooled, gamma, beta, scale, shift, G);
        k_head<<<(G + B - 1) / B, B, 0, stream>>>(pooled, scale, shift,
                                                  fcW1, fcb1, fcW2, fcb2, (float*)d_out, G);
    } else {
        // ---- fallback: atomic scatter (round-4 structure) ----
        char* p = (char*)d_ws;
        int*   degi   = (int*)bump(p, n * 4);
        float* dinv   = (float*)bump(p, n * 4);
        float* agg2   = (float*)bump(p, 2 * n * 4);
        int*   startA = (int*)bump(p, (size_t)(G + 1) * 4);
        float* pooled = (float*)bump(p, (size_t)G * HDIM * 4);
        float* scale  = (float*)bump(p, 2 * HDIM * 4);
        float* shift  = scale + HDIM;
        __half* hA    = (__half*)bump(p, (size_t)HDIM * n * 2);
        __half* hB    = (__half*)bump(p, (size_t)HDIM * n * 2);

        (void)hipMemsetAsync(degi, 0, n * 4, stream);

        k_count<<<(E + B - 1) / B, B, 0, stream>>>(dst, degi, E);
        k_dinv2<<<(ni + B - 1) / B, B, 0, stream>>>(degi, dinv, ni);
        k_start<<<(G + 1 + B - 1) / B, B, 0, stream>>>(batch, startA, ni, G);

        k_self2<<<(2 * ni + B - 1) / B, B, 0, stream>>>(x, dinv, agg2, ni);
        k_edge2<<<(E + B - 1) / B, B, 0, stream>>>(src, dst, x, dinv, agg2, E);
        k_dense2<<<(int)((HDIM * n + B - 1) / B), B, 0, stream>>>(agg2, W1, b1, nullptr, hA, n);

        k_self64h<<<(int)((n * 8 + B - 1) / B), B, 0, stream>>>(hA, dinv, hB, n);
        k_edge64h<<<(int)(((long long)E * 16 + B - 1) / B), B, 0, stream>>>(src, dst, dinv, hA, hB, E);
        k_dense64s<<<4096, B, 0, stream>>>(hB, W2, b2, nullptr, hA, n);

        k_self64h<<<(int)((n * 8 + B - 1) / B), B, 0, stream>>>(hA, dinv, hB, n);
        k_edge64h<<<(int)(((long long)E * 16 + B - 1) / B), B, 0, stream>>>(src, dst, dinv, hA, hB, E);
        k_dense64s<<<4096, B, 0, stream>>>(hB, W3, b3, nullptr, hA, n);

        k_pool_seg<<<G, HDIM, 0, stream>>>(hA, startA, pooled, G);
        k_bnstats<<<HDIM, B, 0, stream>>>(pooled, gamma, beta, scale, shift, G);
        k_head<<<(G + B - 1) / B, B, 0, stream>>>(pooled, scale, shift,
                                                  fcW1, fcb1, fcW2, fcb2, (float*)d_out, G);
    }
}